// Round 1
// baseline (406.323 us; speedup 1.0000x reference)
//
#include <hip/hip_runtime.h>
#include <float.h>

// PretrainingGIN on MI355X — Round 11.
// R10 post-mortem: fused = 3x74us (60%), fetch 187MB @2.9TB/s fabric (h is
// L3-resident). Occupancy metric (39% vs 75% LDS cap) says R9's "TLP probe
// moved nothing" never tested the latency hypothesis. This round attacks
// per-wave in-flight concurrency:
//  (1) degree-rank nodemap: 4 concurrent subgroup nodes have ~equal degree
//      (kills E[max4]/E[mean] ~1.3x divergence waste), waves take even/odd
//      ranks (balanced).
//  (2) software-pipelined gather: prefetch chunk k+1's idx+8 rows before
//      accumulating chunk k (in-flight 8..16 sustained vs 8->0 sawtooth).
//  (3) pad slots point at a real zero row (row N_NODES) -> all per-element
//      degree masks deleted; accumulation unconditional.
// Predicted: fused 74 -> ~58us, FETCH unchanged ~187MB, rate 2.9->3.5TB/s.
// Null => fabric-byte-bound confirmed => next: src-phase partition / fp8.

#define N_NODES 100000
#define N_EDGES 1600000
#define DIM 128
#define NGRAPHS 64
#define PCHUNK 16          // pool stage-1 chunks per graph

#define NBUCK 391          // ceil(100000/256) buckets of 256 nodes
#define BCAP 5120          // max edges/bucket (mean 4096, +16 sigma)
#define CCAP 6144          // ssrc ints per bucket (edges + per-node align pad)
#define EPT 8              // edges per thread in bucket pass
#define EPB 2048           // 256*8 edges per block

#define NB_BUCKET ((N_EDGES + EPB - 1) / EPB)          // 782
#define NB_CAST   (N_NODES * DIM / 4 / 256)            // 12500
#define NB_PACK   (6 * DIM * DIM / 256)                // 384

#define BROWS 32           // rows per fused block (2 waves, interleaved ranks)
#define LSTRIDE 136        // bf16 elems; 272B rows keep 16B align
#define BIDX 1024          // staged indices per BLOCK (sum deg ~560, 17-sigma)

typedef __attribute__((ext_vector_type(8))) short bf16x8;
typedef __attribute__((ext_vector_type(4))) float f32x4;

__device__ inline float bflo(unsigned u) { return __uint_as_float(u << 16); }
__device__ inline float bfhi(unsigned u) { return __uint_as_float(u & 0xffff0000u); }

__device__ inline unsigned short f2bf(float a) {      // RNE
    unsigned u = __float_as_uint(a);
    u = u + 0x7fff + ((u >> 16) & 1);
    return (unsigned short)(u >> 16);
}
__device__ inline unsigned f2bf_pack(float a, float b) {
    unsigned ua = __float_as_uint(a), ub = __float_as_uint(b);
    ua = ua + 0x7fff + ((ua >> 16) & 1);
    ub = ub + 0x7fff + ((ub >> 16) & 1);
    return (ua >> 16) | (ub & 0xffff0000u);
}

// ---------------- super-prep: bucket | cast(+zero row) | pack ----------------
__global__ __launch_bounds__(256) void k_prep(const int* __restrict__ src,
                                              const int* __restrict__ dst,
                                              int* __restrict__ gcnt,
                                              unsigned* __restrict__ store,
                                              const float* __restrict__ x,
                                              unsigned short* __restrict__ hA,
                                              unsigned short* __restrict__ hB,
                                              const float* __restrict__ W1,
                                              const float* __restrict__ W2,
                                              unsigned short* __restrict__ pack) {
    __shared__ int hist[NBUCK];
    __shared__ int base[NBUCK];
    const int t = threadIdx.x;
    const int b = blockIdx.x;

    if (b < NB_BUCKET) {
        // ---- bucket the edges ----
        const int e0 = b * EPB;
        for (int i = t; i < NBUCK; i += 256) hist[i] = 0;
        __syncthreads();

        int bk[EPT], rk[EPT];
        unsigned pk[EPT];
#pragma unroll
        for (int k = 0; k < EPT; ++k) {
            int e = e0 + k * 256 + t;
            bk[k] = -1;
            if (e < N_EDGES) {
                int d = dst[e];
                int s = src[e];
                int bb = d >> 8;
                bk[k] = bb;
                rk[k] = atomicAdd(&hist[bb], 1);
                pk[k] = ((unsigned)(d & 255) << 17) | (unsigned)s;
            }
        }
        __syncthreads();
        for (int i = t; i < NBUCK; i += 256)
            if (hist[i] > 0) base[i] = atomicAdd(&gcnt[i], hist[i]);
        __syncthreads();
#pragma unroll
        for (int k = 0; k < EPT; ++k) {
            if (bk[k] >= 0) {
                int p = base[bk[k]] + rk[k];
                if (p < BCAP) store[(size_t)bk[k] * BCAP + p] = pk[k];
            }
        }
    } else if (b < NB_BUCKET + NB_CAST + 1) {
        // ---- cast x -> bf16; last block zeroes the pad row N_NODES ----
        int i = ((b - NB_BUCKET) * 256 + t) * 4;
        if (i < N_NODES * DIM) {
            float4 v = *(const float4*)(x + i);
            uint2 o;
            o.x = f2bf_pack(v.x, v.y);
            o.y = f2bf_pack(v.z, v.w);
            *(uint2*)(hA + i) = o;
        } else if (i < (N_NODES + 1) * DIM) {
            uint2 z; z.x = 0u; z.y = 0u;
            *(uint2*)(hA + i) = z;
            *(uint2*)(hB + i) = z;
        }
    } else {
        // ---- repack W into B-fragment order bf16 ----
        int tid = (b - NB_BUCKET - NB_CAST - 1) * 256 + t;
        int mat = tid >> 14;
        int e = tid & 16383;
        int k = e >> 7, c = e & 127;
        const float* W = (mat < 3) ? (W1 + mat * DIM * DIM)
                                   : (W2 + (mat - 3) * DIM * DIM);
        int kb = k >> 5, q = (k >> 3) & 3, j = k & 7;
        pack[mat * DIM * DIM + kb * 4096 + c * 32 + q * 8 + j] = f2bf(W[k * DIM + c]);
    }
}

// ------- build pass B: per-bucket CSR fill + zero-row pads + degree ranks -------
__global__ __launch_bounds__(256) void k_csr(const unsigned* __restrict__ store,
                                             const int* __restrict__ gcnt,
                                             int* __restrict__ offs,
                                             int* __restrict__ deg,
                                             int* __restrict__ ssrc,
                                             int* __restrict__ nodemap) {
    __shared__ int hist[256];
    __shared__ int s[256];
    __shared__ int pos[256];
    const int b = blockIdx.x;
    const int t = threadIdx.x;
    int nE = gcnt[b];
    if (nE > BCAP) nE = BCAP;

    hist[t] = 0;
    __syncthreads();
    const unsigned* bs = store + (size_t)b * BCAP;
    for (int e = t; e < nE; e += 256)
        atomicAdd(&hist[bs[e] >> 17], 1);
    __syncthreads();

    int cnt = hist[t];
    int al = (cnt + 3) & ~3;          // 16B-align each node's segment
    s[t] = al;
    __syncthreads();
    for (int off = 1; off < 256; off <<= 1) {
        int x = (t >= off) ? s[t - off] : 0;
        __syncthreads();
        s[t] += x;
        __syncthreads();
    }
    int loc = s[t] - al;              // exclusive prefix
    int node = b * 256 + t;
    if (node < N_NODES) {
        offs[node] = b * CCAP + loc;
        deg[node] = cnt;
    }
    pos[t] = loc;
    __syncthreads();

    int* out = ssrc + (size_t)b * CCAP;
    // pad slots -> the zero row, so the gather needs no per-element masks
    for (int p = cnt; p < al; ++p) out[loc + p] = N_NODES;
    for (int e = t; e < nE; e += 256) {
        unsigned p = bs[e];
        int dl = p >> 17;
        int q = atomicAdd(&pos[dl], 1);
        out[q] = (int)(p & 0x1FFFFu);
    }

    // ---- degree rank within each 32-node group -> nodemap ----
    {
        int c = hist[t];
        int g0 = t & ~31;
        int r = 0;
#pragma unroll 8
        for (int u = 0; u < 32; ++u) {
            int cu = hist[g0 + u];
            r += (cu < c) || (cu == c && (g0 + u) < t);
        }
        nodemap[b * 256 + g0 + r] = b * 256 + t;   // global node id, rank-sorted
    }
}

// ---------------- fused layer: h_out = MLP(h + sum_{j->i} h_j) ----------------
__global__ __launch_bounds__(128) void k_fused(const unsigned short* __restrict__ h,
                                               const int* __restrict__ offs,
                                               const int* __restrict__ deg,
                                               const int* __restrict__ ssrc,
                                               const int* __restrict__ nodemap,
                                               unsigned short* __restrict__ hout,
                                               const unsigned short* __restrict__ Wp1,
                                               const float* __restrict__ b1,
                                               const unsigned short* __restrict__ Wp2,
                                               const float* __restrict__ b2,
                                               int relu_out) {
    __shared__ int idx[BIDX];                         // 4096 B (block-shared)
    __shared__ unsigned short buf[BROWS * LSTRIDE];   // 8704 B
    const int tid = threadIdx.x;
    const int wv = tid >> 6, lane = tid & 63;
    const int q = lane >> 4, n = lane & 15;
    const int sub = lane >> 4, ln16 = lane & 15;
    const int row0 = blockIdx.x * BROWS;

    // ---- stage the BLOCK's indices (contiguous CSR range incl. last pads) ----
    const int base0 = offs[row0];
    int cnt = offs[row0 + 31] + ((deg[row0 + 31] + 3) & ~3) - base0;
    if (cnt > BIDX) cnt = BIDX;
    for (int i = tid * 4; i < cnt; i += 512)
        *(int4*)&idx[i] = *(const int4*)(ssrc + base0 + i);
    __syncthreads();

#define ROWLD(S) (*(const uint4*)(h + (size_t)min((S) & 0x1FFFF, N_NODES) * DIM + ln16 * 8))
#define ACCU(RK) { a0 += bflo(RK.x); a1 += bfhi(RK.x); a2 += bflo(RK.y); a3 += bfhi(RK.y); \
                   a4 += bflo(RK.z); a5 += bfhi(RK.z); a6 += bflo(RK.w); a7 += bfhi(RK.w); }

    // ---- gather: degree-rank-matched subgroups + 1-chunk-ahead pipeline ----
#pragma unroll 1
    for (int j = 0; j < 4; ++j) {
        const int nd = nodemap[row0 + (j * 4 + sub) * 2 + wv];  // rank-adjacent
        const int lr = nd - row0;                               // buf row
        const unsigned short* hb = h + (size_t)nd * DIM + ln16 * 8;
        uint4 sv = *(const uint4*)hb;
        float a0 = bflo(sv.x), a1 = bfhi(sv.x);
        float a2 = bflo(sv.y), a3 = bfhi(sv.y);
        float a4 = bflo(sv.z), a5 = bfhi(sv.z);
        float a6 = bflo(sv.w), a7 = bfhi(sv.w);

        int loc = offs[nd] - base0;                   // 4-aligned
        if (loc > BIDX - 8) loc = BIDX - 8;           // safety (never in practice)
        const int bound4 = (deg[nd] + 3) & ~3;        // == node's padded segment

        int e = 0;
        uint4 r0, r1, r2, r3, r4, r5, r6, r7;
        bool have = (8 <= bound4);
        if (have) {                                   // prime: chunk 0 in flight
            int4 iA = *(const int4*)&idx[loc];
            int4 iB = *(const int4*)&idx[loc + 4];
            r0 = ROWLD(iA.x); r1 = ROWLD(iA.y); r2 = ROWLD(iA.z); r3 = ROWLD(iA.w);
            r4 = ROWLD(iB.x); r5 = ROWLD(iB.y); r6 = ROWLD(iB.z); r7 = ROWLD(iB.w);
        }
        while (have) {
            const int en = e + 8;
            const bool hn = (en + 8 <= bound4);
            uint4 t0, t1, t2, t3, t4, t5, t6, t7;
            if (hn) {                                 // issue next chunk first
                int4 iA = *(const int4*)&idx[loc + en];
                int4 iB = *(const int4*)&idx[loc + en + 4];
                t0 = ROWLD(iA.x); t1 = ROWLD(iA.y); t2 = ROWLD(iA.z); t3 = ROWLD(iA.w);
                t4 = ROWLD(iB.x); t5 = ROWLD(iB.y); t6 = ROWLD(iB.z); t7 = ROWLD(iB.w);
            }
            ACCU(r0) ACCU(r1) ACCU(r2) ACCU(r3)       // consume current chunk
            ACCU(r4) ACCU(r5) ACCU(r6) ACCU(r7)
            if (hn) { r0 = t0; r1 = t1; r2 = t2; r3 = t3;
                      r4 = t4; r5 = t5; r6 = t6; r7 = t7; }
            e = en; have = hn;
        }
        if (e < bound4) {                             // one 4-chunk tail
            int4 iA = *(const int4*)&idx[loc + e];
            uint4 u0 = ROWLD(iA.x), u1 = ROWLD(iA.y);
            uint4 u2 = ROWLD(iA.z), u3 = ROWLD(iA.w);
            ACCU(u0) ACCU(u1) ACCU(u2) ACCU(u3)
        }

        uint4 o;
        o.x = f2bf_pack(a0, a1);
        o.y = f2bf_pack(a2, a3);
        o.z = f2bf_pack(a4, a5);
        o.w = f2bf_pack(a6, a7);
        *(uint4*)&buf[lr * LSTRIDE + ln16 * 8] = o;
    }
#undef ROWLD
#undef ACCU
    __syncthreads();                                  // buf rows are cross-wave now

    // ---- A1 fragments ----
    bf16x8 a1f[4];
    {
        const unsigned short* mr = buf + (wv * 16 + n) * LSTRIDE + q * 8;
#pragma unroll
        for (int kb = 0; kb < 4; ++kb) a1f[kb] = *(const bf16x8*)(mr + kb * 32);
    }

    float bia1[8], bia2[8];
#pragma unroll
    for (int ct = 0; ct < 8; ++ct) {
        bia1[ct] = b1[ct * 16 + n];
        bia2[ct] = b2[ct * 16 + n];
    }

    // ---- GEMM1 ----
#pragma unroll
    for (int ct = 0; ct < 8; ++ct) {
        f32x4 acc = {0.f, 0.f, 0.f, 0.f};
#pragma unroll
        for (int kb = 0; kb < 4; ++kb) {
            bf16x8 bfr = *(const bf16x8*)(Wp1 + kb * 4096 + (ct * 16 + n) * 32 + q * 8);
            acc = __builtin_amdgcn_mfma_f32_16x16x32_bf16(a1f[kb], bfr, acc, 0, 0, 0);
        }
#pragma unroll
        for (int r = 0; r < 4; ++r)
            buf[(wv * 16 + q * 4 + r) * LSTRIDE + ct * 16 + n] =
                f2bf(fmaxf(acc[r] + bia1[ct], 0.f));
    }

    // ---- A2 fragments ----
    bf16x8 a2f[4];
    {
        const unsigned short* tr = buf + (wv * 16 + n) * LSTRIDE + q * 8;
#pragma unroll
        for (int kb = 0; kb < 4; ++kb) a2f[kb] = *(const bf16x8*)(tr + kb * 32);
    }

    // ---- GEMM2 ----
#pragma unroll
    for (int ct = 0; ct < 8; ++ct) {
        f32x4 acc = {0.f, 0.f, 0.f, 0.f};
#pragma unroll
        for (int kb = 0; kb < 4; ++kb) {
            bf16x8 bfr = *(const bf16x8*)(Wp2 + kb * 4096 + (ct * 16 + n) * 32 + q * 8);
            acc = __builtin_amdgcn_mfma_f32_16x16x32_bf16(a2f[kb], bfr, acc, 0, 0, 0);
        }
#pragma unroll
        for (int r = 0; r < 4; ++r) {
            float v = acc[r] + bia2[ct];
            if (relu_out) v = fmaxf(v, 0.f);
            buf[(wv * 16 + q * 4 + r) * LSTRIDE + ct * 16 + n] = f2bf(v);
        }
    }

    // ---- store own wave's 16 rows ----
    {
#pragma unroll
        for (int st = 0; st < 4; ++st) {
            int lr2 = wv * 16 + st * 4 + (lane >> 4);
            int c0 = (lane & 15) * 8;
            *(bf16x8*)(hout + (size_t)(row0 + lr2) * DIM + c0) =
                *(const bf16x8*)(buf + lr2 * LSTRIDE + c0);
        }
    }
}

// ---------------- pool ----------------
__device__ inline int lbound(const int* __restrict__ batch, int g) {
    int lo = 0, hi = N_NODES;
    while (lo < hi) {
        int mid = (lo + hi) >> 1;
        if (batch[mid] < g) lo = mid + 1;
        else hi = mid;
    }
    return lo;
}

__global__ __launch_bounds__(256) void k_pool1(const unsigned short* __restrict__ h,
                                               const int* __restrict__ batch,
                                               float* __restrict__ partial) {
    __shared__ float red[4][DIM];
    __shared__ int sb[2];
    int g = blockIdx.x, c = blockIdx.y;
    int t = threadIdx.x;
    if (t < 2) sb[t] = lbound(batch, g + t);
    __syncthreads();
    int i0 = sb[0], i1 = sb[1];
    int rowpar = t >> 6;
    int col = (t & 63) * 2;
    float mx = -FLT_MAX, my = -FLT_MAX;
    for (int i = i0 + c * 4 + rowpar; i < i1; i += 64) {
        unsigned u = *(const unsigned*)(h + (size_t)i * DIM + col);
        mx = fmaxf(mx, bflo(u));
        my = fmaxf(my, bfhi(u));
    }
    red[rowpar][col] = mx;
    red[rowpar][col + 1] = my;
    __syncthreads();
    if (rowpar == 0) {
        mx = fmaxf(fmaxf(red[0][col], red[1][col]), fmaxf(red[2][col], red[3][col]));
        my = fmaxf(fmaxf(red[0][col + 1], red[1][col + 1]),
                   fmaxf(red[2][col + 1], red[3][col + 1]));
        float* p = partial + ((size_t)g * PCHUNK + c) * DIM;
        p[col] = mx;
        p[col + 1] = my;
    }
}

__global__ __launch_bounds__(128) void k_pool2(const float* __restrict__ partial,
                                               float* __restrict__ out) {
    int g = blockIdx.x;
    int col = threadIdx.x;
    const float* p = partial + (size_t)g * PCHUNK * DIM + col;
    float m = p[0];
#pragma unroll
    for (int c = 1; c < PCHUNK; ++c) m = fmaxf(m, p[c * DIM]);
    out[g * DIM + col] = m;
}

extern "C" void kernel_launch(void* const* d_in, const int* in_sizes, int n_in,
                              void* d_out, int out_size, void* d_ws, size_t ws_size,
                              hipStream_t stream) {
    const float* x   = (const float*)d_in[0];
    const int* ei    = (const int*)d_in[1];
    const int* batch = (const int*)d_in[2];
    const float* W1  = (const float*)d_in[3];
    const float* b1  = (const float*)d_in[4];
    const float* W2  = (const float*)d_in[5];
    const float* b2  = (const float*)d_in[6];
    float* out = (float*)d_out;

    const int src_n = 0;  (void)src_n;
    const int* src = ei;
    const int* dst = ei + N_EDGES;

    unsigned short* hA  = (unsigned short*)d_ws;                        // (N+1) rows
    unsigned short* hB  = hA + (size_t)(N_NODES + 1) * DIM;             // (N+1) rows
    unsigned* store     = (unsigned*)(hB + (size_t)(N_NODES + 1) * DIM);
    int* ssrc           = (int*)(store + (size_t)NBUCK * BCAP);
    int* offs           = ssrc + (size_t)NBUCK * CCAP + 64;
    int* deg            = offs + N_NODES;
    int* nodemap        = deg + N_NODES;                                // NBUCK*256
    int* gcnt           = nodemap + NBUCK * 256;                        // padded 400
    unsigned short* wpk = (unsigned short*)(gcnt + 400);                // 16B aligned
    float* partial      = (float*)(wpk + 6 * DIM * DIM);

    // prep: async memset of gcnt, fused bucket|cast+zero|pack, per-bucket CSR
    hipMemsetAsync(gcnt, 0, NBUCK * sizeof(int), stream);
    k_prep<<<NB_BUCKET + NB_CAST + 1 + NB_PACK, 256, 0, stream>>>(
        src, dst, gcnt, store, x, hA, hB, W1, W2, wpk);
    k_csr<<<NBUCK, 256, 0, stream>>>(store, gcnt, offs, deg, ssrc, nodemap);

    const int fusedBlocks = N_NODES / BROWS;   // 3125 exactly
    unsigned short* Wp1 = wpk;
    unsigned short* Wp2 = wpk + 3 * DIM * DIM;

    // 3 fused layers, ping-pong hA <-> hB
    k_fused<<<fusedBlocks, 128, 0, stream>>>(hA, offs, deg, ssrc, nodemap, hB,
                                             Wp1, b1, Wp2, b2, 1);
    k_fused<<<fusedBlocks, 128, 0, stream>>>(hB, offs, deg, ssrc, nodemap, hA,
                                             Wp1 + DIM * DIM, b1 + DIM,
                                             Wp2 + DIM * DIM, b2 + DIM, 1);
    k_fused<<<fusedBlocks, 128, 0, stream>>>(hA, offs, deg, ssrc, nodemap, hB,
                                             Wp1 + 2 * DIM * DIM, b1 + 2 * DIM,
                                             Wp2 + 2 * DIM * DIM, b2 + 2 * DIM, 0);

    // two-stage pool
    {
        dim3 g1(NGRAPHS, PCHUNK);
        k_pool1<<<g1, 256, 0, stream>>>(hB, batch, partial);
        k_pool2<<<NGRAPHS, 128, 0, stream>>>(partial, out);
    }
}

// Round 3
// 335.470 us; speedup vs baseline: 1.2112x; 1.2112x over previous
//
#include <hip/hip_runtime.h>
#include <float.h>

// PretrainingGIN on MI355X — Round 13.
// R12 never ran (container failed twice; infra timings were pathological).
// R13 = same byte-reduction thesis, de-risked: ALL-int8 h representation
// (q8 row 128B + per-row f32 scale). Hybrid bf16-self bought ~nothing: the
// 16 gathered q8 rows dominate quant error, self is 1/17 of the sum. Drops
// both bf16 ping-pong buffers -> workspace 45.5MB (< 71MB known-good R10),
// kills the ws-overflow hypothesis for the R12 crash. Pool dequants q8.
// Compulsory fetch floor/layer: 8 XCD x 13.2MB vs 8 x 25.6MB.
// Predicted k_fused: FETCH 187->~110MB, WRITE 25->~14MB, dur 74->~45-52us,
// VALUBusy 37->65-85% (dequant = bfe+cvt+fmac = 3 VALU/elem ~= 41us floor).
// Fail-verify => int8 dead, revert bf16 + declare fabric roofline.
// VALUBusy>85% => next: packed-u16 int accumulation / i8-MFMA.

#define N_NODES 100000
#define N_EDGES 1600000
#define DIM 128
#define NGRAPHS 64
#define PCHUNK 16          // pool stage-1 chunks per graph

#define NBUCK 391          // ceil(100000/256) buckets of 256 nodes
#define BCAP 5120          // max edges/bucket (mean 4096, +16 sigma)
#define CCAP 6144          // ssrc ints per bucket (edges + per-node align pad)
#define EPT 8              // edges per thread in bucket pass
#define EPB 2048           // 256*8 edges per block

#define NB_BUCKET ((N_EDGES + EPB - 1) / EPB)          // 782
#define NB_CAST   (N_NODES * DIM / 4 / 256)            // 12500
#define NB_PACK   (6 * DIM * DIM / 256)                // 384

#define BROWS 32           // rows per fused block (16 per wave, 2 waves)
#define LSTRIDE 136        // bf16 elems; 272B rows keep 16B align
#define IDXCAP 512         // staged indices per wave (sum deg ~280, 14-sigma)

typedef __attribute__((ext_vector_type(8))) short bf16x8;
typedef __attribute__((ext_vector_type(4))) float f32x4;

__device__ inline float bflo(unsigned u) { return __uint_as_float(u << 16); }
__device__ inline float bfhi(unsigned u) { return __uint_as_float(u & 0xffff0000u); }

__device__ inline unsigned short f2bf(float a) {      // RNE
    unsigned u = __float_as_uint(a);
    u = u + 0x7fff + ((u >> 16) & 1);
    return (unsigned short)(u >> 16);
}
__device__ inline unsigned f2bf_pack(float a, float b) {
    unsigned ua = __float_as_uint(a), ub = __float_as_uint(b);
    ua = ua + 0x7fff + ((ua >> 16) & 1);
    ub = ub + 0x7fff + ((ub >> 16) & 1);
    return (ua >> 16) | (ub & 0xffff0000u);
}

// signed byte k of word w -> float (v_bfe_i32 + v_cvt_f32_i32)
__device__ inline float i8b(unsigned w, int k) {
    return (float)((int)(w << (24 - 8 * k)) >> 24);
}
__device__ inline int qz(float f, float inv) {
    float r = rintf(f * inv);
    r = fminf(fmaxf(r, -127.f), 127.f);
    return (int)r;
}
__device__ inline unsigned pack4(int q0, int q1, int q2, int q3) {
    return ((unsigned)q0 & 255u) | (((unsigned)q1 & 255u) << 8) |
           (((unsigned)q2 & 255u) << 16) | (((unsigned)q3 & 255u) << 24);
}

// -------- super-prep: bucket | cast->q8 (+zero pad row) | pack --------
__global__ __launch_bounds__(256) void k_prep(const int* __restrict__ src,
                                              const int* __restrict__ dst,
                                              int* __restrict__ gcnt,
                                              unsigned* __restrict__ store,
                                              const float* __restrict__ x,
                                              unsigned char* __restrict__ q8A,
                                              unsigned char* __restrict__ q8B,
                                              float* __restrict__ sA,
                                              float* __restrict__ sB,
                                              const float* __restrict__ W1,
                                              const float* __restrict__ W2,
                                              unsigned short* __restrict__ pack) {
    __shared__ int hist[NBUCK];
    __shared__ int base[NBUCK];
    const int t = threadIdx.x;
    const int b = blockIdx.x;

    if (b < NB_BUCKET) {
        // ---- bucket the edges ----
        const int e0 = b * EPB;
        for (int i = t; i < NBUCK; i += 256) hist[i] = 0;
        __syncthreads();

        int bk[EPT], rk[EPT];
        unsigned pk[EPT];
#pragma unroll
        for (int k = 0; k < EPT; ++k) {
            int e = e0 + k * 256 + t;
            bk[k] = -1;
            if (e < N_EDGES) {
                int d = dst[e];
                int s = src[e];
                int bb = d >> 8;
                bk[k] = bb;
                rk[k] = atomicAdd(&hist[bb], 1);
                pk[k] = ((unsigned)(d & 255) << 17) | (unsigned)s;
            }
        }
        __syncthreads();
        for (int i = t; i < NBUCK; i += 256)
            if (hist[i] > 0) base[i] = atomicAdd(&gcnt[i], hist[i]);
        __syncthreads();
#pragma unroll
        for (int k = 0; k < EPT; ++k) {
            if (bk[k] >= 0) {
                int p = base[bk[k]] + rk[k];
                if (p < BCAP) store[(size_t)bk[k] * BCAP + p] = pk[k];
            }
        }
    } else if (b < NB_BUCKET + NB_CAST + 1) {
        int bi = b - NB_BUCKET;
        if (bi < NB_CAST) {
            // ---- cast x -> per-row-sym int8 (row = 32 consecutive threads) --
            int i = (bi * 256 + t) * 4;
            float4 v = *(const float4*)(x + i);
            float am = fmaxf(fmaxf(fabsf(v.x), fabsf(v.y)),
                             fmaxf(fabsf(v.z), fabsf(v.w)));
            am = fmaxf(am, __shfl_xor(am, 1));
            am = fmaxf(am, __shfl_xor(am, 2));
            am = fmaxf(am, __shfl_xor(am, 4));
            am = fmaxf(am, __shfl_xor(am, 8));
            am = fmaxf(am, __shfl_xor(am, 16));      // 32-thread row group
            float inv = am > 0.f ? 127.f / am : 0.f;
            *(unsigned*)(q8A + i) =
                pack4(qz(v.x, inv), qz(v.y, inv), qz(v.z, inv), qz(v.w, inv));
            if ((t & 31) == 0) sA[i >> 7] = am * (1.f / 127.f);
        } else {
            // ---- zero the pad row N_NODES in both q8 tables ----
            if (t < 32) {
                *(unsigned*)(q8A + (size_t)N_NODES * DIM + t * 4) = 0u;
                *(unsigned*)(q8B + (size_t)N_NODES * DIM + t * 4) = 0u;
            }
            if (t == 0) { sA[N_NODES] = 0.f; sB[N_NODES] = 0.f; }
        }
    } else {
        // ---- repack W into B-fragment order bf16 ----
        int tid = (b - NB_BUCKET - NB_CAST - 1) * 256 + t;
        int mat = tid >> 14;
        int e = tid & 16383;
        int k = e >> 7, c = e & 127;
        const float* W = (mat < 3) ? (W1 + mat * DIM * DIM)
                                   : (W2 + (mat - 3) * DIM * DIM);
        int kb = k >> 5, q = (k >> 3) & 3, j = k & 7;
        pack[mat * DIM * DIM + kb * 4096 + c * 32 + q * 8 + j] = f2bf(W[k * DIM + c]);
    }
}

// -------- build pass B: per-bucket CSR fill + zero-row pads --------
__global__ __launch_bounds__(256) void k_csr(const unsigned* __restrict__ store,
                                             const int* __restrict__ gcnt,
                                             int* __restrict__ offs,
                                             int* __restrict__ deg,
                                             int* __restrict__ ssrc) {
    __shared__ int hist[256];
    __shared__ int s[256];
    __shared__ int pos[256];
    const int b = blockIdx.x;
    const int t = threadIdx.x;
    int nE = gcnt[b];
    if (nE > BCAP) nE = BCAP;

    hist[t] = 0;
    __syncthreads();
    const unsigned* bs = store + (size_t)b * BCAP;
    for (int e = t; e < nE; e += 256)
        atomicAdd(&hist[bs[e] >> 17], 1);
    __syncthreads();

    int cnt = hist[t];
    int al = (cnt + 3) & ~3;          // 16B-align each node's segment
    s[t] = al;
    __syncthreads();
    for (int off = 1; off < 256; off <<= 1) {
        int x = (t >= off) ? s[t - off] : 0;
        __syncthreads();
        s[t] += x;
        __syncthreads();
    }
    int loc = s[t] - al;              // exclusive prefix
    int node = b * 256 + t;
    if (node < N_NODES) {
        offs[node] = b * CCAP + loc;
        deg[node] = cnt;
    }
    pos[t] = loc;
    __syncthreads();

    int* out = ssrc + (size_t)b * CCAP;
    // pad slots -> zero row, so the gather needs no per-element masks
    for (int p = cnt; p < al; ++p) out[loc + p] = N_NODES;
    for (int e = t; e < nE; e += 256) {
        unsigned p = bs[e];
        int dl = p >> 17;
        int q = atomicAdd(&pos[dl], 1);
        out[q] = (int)(p & 0x1FFFFu);
    }
}

// ---------------- fused layer: h_out = MLP(h + sum_{j->i} h_j) ----------------
// h lives as int8 rows (128B) + per-row f32 scale. In q8/qs, out q8o/qso.
__global__ __launch_bounds__(128) void k_fused(const unsigned char* __restrict__ q8,
                                               const float* __restrict__ qs,
                                               const int* __restrict__ offs,
                                               const int* __restrict__ deg,
                                               const int* __restrict__ ssrc,
                                               unsigned char* __restrict__ q8o,
                                               float* __restrict__ qso,
                                               const unsigned short* __restrict__ Wp1,
                                               const float* __restrict__ b1,
                                               const unsigned short* __restrict__ Wp2,
                                               const float* __restrict__ b2,
                                               int relu_out) {
    __shared__ int idx[2][IDXCAP];                    // 4096 B
    __shared__ unsigned short buf[BROWS * LSTRIDE];   // 8704 B
    const int tid = threadIdx.x;
    const int wv = tid >> 6, lane = tid & 63;
    const int q = lane >> 4, n = lane & 15;
    const int sub = lane >> 4, ln16 = lane & 15;
    const int row0 = blockIdx.x * BROWS;
    const int nb0 = row0 + wv * 16;                   // wave's first node

    // ---- stage the wave's indices (contiguous CSR range incl. pads) ----
    const int base0 = offs[nb0];
    int cnt = offs[nb0 + 15] + ((deg[nb0 + 15] + 3) & ~3) - base0;
    if (cnt > IDXCAP) cnt = IDXCAP;
    for (int i = lane * 4; i < cnt; i += 256) {
        int4 v = *(const int4*)(ssrc + base0 + i);
        *(int4*)&idx[wv][i] = v;
    }

#define ACCQ(U, S) { a0 += (S) * i8b(U.x, 0); a1 += (S) * i8b(U.x, 1); \
                     a2 += (S) * i8b(U.x, 2); a3 += (S) * i8b(U.x, 3); \
                     a4 += (S) * i8b(U.y, 0); a5 += (S) * i8b(U.y, 1); \
                     a6 += (S) * i8b(U.y, 2); a7 += (S) * i8b(U.y, 3); }
#define ROWQ(S) (*(const uint2*)(q8 + (size_t)(S) * DIM + ln16 * 8))

    // ---- gather: 4 iterations x 4 parallel rows; per-node bounds ----
#pragma unroll 1
    for (int j = 0; j < 4; ++j) {
        const int node = nb0 + j * 4 + sub;
        uint2 sv = ROWQ(node);
        float ssf = qs[node];
        float a0 = ssf * i8b(sv.x, 0), a1 = ssf * i8b(sv.x, 1);
        float a2 = ssf * i8b(sv.x, 2), a3 = ssf * i8b(sv.x, 3);
        float a4 = ssf * i8b(sv.y, 0), a5 = ssf * i8b(sv.y, 1);
        float a6 = ssf * i8b(sv.y, 2), a7 = ssf * i8b(sv.y, 3);

        int loc = offs[node] - base0;                 // 4-aligned
        const int bound4 = (deg[node] + 3) & ~3;      // padded segment
        if (loc > IDXCAP - 8) loc = IDXCAP - 8;       // safety (never in practice)

        int e = 0;
        for (; e + 8 <= bound4; e += 8) {
            int4 iA = *(const int4*)&idx[wv][loc + e];
            int4 iB = *(const int4*)&idx[wv][loc + e + 4];
            int s0 = min(iA.x & 0x1FFFF, N_NODES);
            int s1 = min(iA.y & 0x1FFFF, N_NODES);
            int s2 = min(iA.z & 0x1FFFF, N_NODES);
            int s3 = min(iA.w & 0x1FFFF, N_NODES);
            int s4 = min(iB.x & 0x1FFFF, N_NODES);
            int s5 = min(iB.y & 0x1FFFF, N_NODES);
            int s6 = min(iB.z & 0x1FFFF, N_NODES);
            int s7 = min(iB.w & 0x1FFFF, N_NODES);
            uint2 u0 = ROWQ(s0); uint2 u1 = ROWQ(s1);
            uint2 u2 = ROWQ(s2); uint2 u3 = ROWQ(s3);
            uint2 u4 = ROWQ(s4); uint2 u5 = ROWQ(s5);
            uint2 u6 = ROWQ(s6); uint2 u7 = ROWQ(s7);
            float c0 = qs[s0], c1 = qs[s1], c2 = qs[s2], c3 = qs[s3];
            float c4 = qs[s4], c5 = qs[s5], c6 = qs[s6], c7 = qs[s7];
            ACCQ(u0, c0) ACCQ(u1, c1) ACCQ(u2, c2) ACCQ(u3, c3)
            ACCQ(u4, c4) ACCQ(u5, c5) ACCQ(u6, c6) ACCQ(u7, c7)
        }
        if (e < bound4) {                             // one 4-chunk tail
            int4 iA = *(const int4*)&idx[wv][loc + e];
            int s0 = min(iA.x & 0x1FFFF, N_NODES);
            int s1 = min(iA.y & 0x1FFFF, N_NODES);
            int s2 = min(iA.z & 0x1FFFF, N_NODES);
            int s3 = min(iA.w & 0x1FFFF, N_NODES);
            uint2 u0 = ROWQ(s0); uint2 u1 = ROWQ(s1);
            uint2 u2 = ROWQ(s2); uint2 u3 = ROWQ(s3);
            float c0 = qs[s0], c1 = qs[s1], c2 = qs[s2], c3 = qs[s3];
            ACCQ(u0, c0) ACCQ(u1, c1) ACCQ(u2, c2) ACCQ(u3, c3)
        }

        uint4 o;
        o.x = f2bf_pack(a0, a1);
        o.y = f2bf_pack(a2, a3);
        o.z = f2bf_pack(a4, a5);
        o.w = f2bf_pack(a6, a7);
        *(uint4*)&buf[(wv * 16 + j * 4 + sub) * LSTRIDE + ln16 * 8] = o;
    }
#undef ROWQ
#undef ACCQ

    // ---- A1 fragments ----
    bf16x8 a1f[4];
    {
        const unsigned short* mr = buf + (wv * 16 + n) * LSTRIDE + q * 8;
#pragma unroll
        for (int kb = 0; kb < 4; ++kb) a1f[kb] = *(const bf16x8*)(mr + kb * 32);
    }

    float bia1[8], bia2[8];
#pragma unroll
    for (int ct = 0; ct < 8; ++ct) {
        bia1[ct] = b1[ct * 16 + n];
        bia2[ct] = b2[ct * 16 + n];
    }

    // ---- GEMM1 ----
#pragma unroll
    for (int ct = 0; ct < 8; ++ct) {
        f32x4 acc = {0.f, 0.f, 0.f, 0.f};
#pragma unroll
        for (int kb = 0; kb < 4; ++kb) {
            bf16x8 bfr = *(const bf16x8*)(Wp1 + kb * 4096 + (ct * 16 + n) * 32 + q * 8);
            acc = __builtin_amdgcn_mfma_f32_16x16x32_bf16(a1f[kb], bfr, acc, 0, 0, 0);
        }
#pragma unroll
        for (int r = 0; r < 4; ++r)
            buf[(wv * 16 + q * 4 + r) * LSTRIDE + ct * 16 + n] =
                f2bf(fmaxf(acc[r] + bia1[ct], 0.f));
    }

    // ---- A2 fragments ----
    bf16x8 a2f[4];
    {
        const unsigned short* tr = buf + (wv * 16 + n) * LSTRIDE + q * 8;
#pragma unroll
        for (int kb = 0; kb < 4; ++kb) a2f[kb] = *(const bf16x8*)(tr + kb * 32);
    }

    // ---- GEMM2 ----
#pragma unroll
    for (int ct = 0; ct < 8; ++ct) {
        f32x4 acc = {0.f, 0.f, 0.f, 0.f};
#pragma unroll
        for (int kb = 0; kb < 4; ++kb) {
            bf16x8 bfr = *(const bf16x8*)(Wp2 + kb * 4096 + (ct * 16 + n) * 32 + q * 8);
            acc = __builtin_amdgcn_mfma_f32_16x16x32_bf16(a2f[kb], bfr, acc, 0, 0, 0);
        }
#pragma unroll
        for (int r = 0; r < 4; ++r) {
            float v = acc[r] + bia2[ct];
            if (relu_out) v = fmaxf(v, 0.f);
            buf[(wv * 16 + q * 4 + r) * LSTRIDE + ct * 16 + n] = f2bf(v);
        }
    }

    // ---- store own wave's 16 rows as q8 + per-row scale ----
    {
#pragma unroll
        for (int st = 0; st < 4; ++st) {
            int lr = wv * 16 + st * 4 + (lane >> 4);
            int c0 = (lane & 15) * 8;
            uint4 w = *(const uint4*)(buf + lr * LSTRIDE + c0);
            float f0 = bflo(w.x), f1 = bfhi(w.x);
            float f2 = bflo(w.y), f3 = bfhi(w.y);
            float f4 = bflo(w.z), f5 = bfhi(w.z);
            float f6 = bflo(w.w), f7 = bfhi(w.w);
            float am = fmaxf(fmaxf(fmaxf(fabsf(f0), fabsf(f1)),
                                   fmaxf(fabsf(f2), fabsf(f3))),
                             fmaxf(fmaxf(fabsf(f4), fabsf(f5)),
                                   fmaxf(fabsf(f6), fabsf(f7))));
            am = fmaxf(am, __shfl_xor(am, 1));
            am = fmaxf(am, __shfl_xor(am, 2));
            am = fmaxf(am, __shfl_xor(am, 4));
            am = fmaxf(am, __shfl_xor(am, 8));       // 16-lane row group
            float inv = am > 0.f ? 127.f / am : 0.f;
            uint2 qq;
            qq.x = pack4(qz(f0, inv), qz(f1, inv), qz(f2, inv), qz(f3, inv));
            qq.y = pack4(qz(f4, inv), qz(f5, inv), qz(f6, inv), qz(f7, inv));
            *(uint2*)(q8o + (size_t)(row0 + lr) * DIM + c0) = qq;
            if ((lane & 15) == 0) qso[row0 + lr] = am * (1.f / 127.f);
        }
    }
}

// ---------------- pool (dequantizing q8 directly) ----------------
__device__ inline int lbound(const int* __restrict__ batch, int g) {
    int lo = 0, hi = N_NODES;
    while (lo < hi) {
        int mid = (lo + hi) >> 1;
        if (batch[mid] < g) lo = mid + 1;
        else hi = mid;
    }
    return lo;
}

__global__ __launch_bounds__(256) void k_pool1(const unsigned char* __restrict__ q8,
                                               const float* __restrict__ qs,
                                               const int* __restrict__ batch,
                                               float* __restrict__ partial) {
    __shared__ float red[8][DIM];
    __shared__ int sb[2];
    int g = blockIdx.x, c = blockIdx.y;
    int t = threadIdx.x;
    if (t < 2) sb[t] = lbound(batch, g + t);
    __syncthreads();
    int i0 = sb[0], i1 = sb[1];
    int rp = t >> 5;                 // 8 rows in parallel
    int col = (t & 31) * 4;          // 4 cols/thread
    float m0 = -FLT_MAX, m1 = -FLT_MAX, m2 = -FLT_MAX, m3 = -FLT_MAX;
    for (int i = i0 + c * 8 + rp; i < i1; i += 128) {
        unsigned u = *(const unsigned*)(q8 + (size_t)i * DIM + col);
        float s = qs[i];
        m0 = fmaxf(m0, s * i8b(u, 0));
        m1 = fmaxf(m1, s * i8b(u, 1));
        m2 = fmaxf(m2, s * i8b(u, 2));
        m3 = fmaxf(m3, s * i8b(u, 3));
    }
    red[rp][col] = m0;  red[rp][col + 1] = m1;
    red[rp][col + 2] = m2;  red[rp][col + 3] = m3;
    __syncthreads();
    if (rp == 0) {
#pragma unroll
        for (int r = 1; r < 8; ++r) {
            m0 = fmaxf(m0, red[r][col]);
            m1 = fmaxf(m1, red[r][col + 1]);
            m2 = fmaxf(m2, red[r][col + 2]);
            m3 = fmaxf(m3, red[r][col + 3]);
        }
        float* p = partial + ((size_t)g * PCHUNK + c) * DIM;
        p[col] = m0;  p[col + 1] = m1;  p[col + 2] = m2;  p[col + 3] = m3;
    }
}

__global__ __launch_bounds__(128) void k_pool2(const float* __restrict__ partial,
                                               float* __restrict__ out) {
    int g = blockIdx.x;
    int col = threadIdx.x;
    const float* p = partial + (size_t)g * PCHUNK * DIM + col;
    float m = p[0];
#pragma unroll
    for (int c = 1; c < PCHUNK; ++c) m = fmaxf(m, p[c * DIM]);
    out[g * DIM + col] = m;
}

extern "C" void kernel_launch(void* const* d_in, const int* in_sizes, int n_in,
                              void* d_out, int out_size, void* d_ws, size_t ws_size,
                              hipStream_t stream) {
    const float* x   = (const float*)d_in[0];
    const int* ei    = (const int*)d_in[1];
    const int* batch = (const int*)d_in[2];
    const float* W1  = (const float*)d_in[3];
    const float* b1  = (const float*)d_in[4];
    const float* W2  = (const float*)d_in[5];
    const float* b2  = (const float*)d_in[6];
    float* out = (float*)d_out;

    const int* src = ei;
    const int* dst = ei + N_EDGES;

    const size_t NROW = (size_t)(N_NODES + 1);
    unsigned char* q8A  = (unsigned char*)d_ws;                     // 12.8 MB
    unsigned char* q8B  = q8A + NROW * DIM;                         // 12.8 MB
    unsigned* store     = (unsigned*)(q8B + NROW * DIM);            // 8.0 MB
    int* ssrc           = (int*)(store + (size_t)NBUCK * BCAP);     // 9.6 MB
    int* offs           = ssrc + (size_t)NBUCK * CCAP;              // 400 KB
    int* deg            = offs + N_NODES;                           // 400 KB
    int* gcnt           = deg + N_NODES;                            // 400 ints
    unsigned short* wpk = (unsigned short*)(gcnt + 400);            // 192 KB
    float* partial      = (float*)(wpk + 6 * DIM * DIM);            // 512 KB
    float* sA           = partial + (size_t)NGRAPHS * PCHUNK * DIM; // 400 KB
    float* sB           = sA + NROW;                                // 400 KB
    // total ~45.5 MB (< 71 MB known-good R10 footprint)

    // prep: async memset of gcnt, fused bucket|cast+quant|pack, per-bucket CSR
    hipMemsetAsync(gcnt, 0, NBUCK * sizeof(int), stream);
    k_prep<<<NB_BUCKET + NB_CAST + 1 + NB_PACK, 256, 0, stream>>>(
        src, dst, gcnt, store, x, q8A, q8B, sA, sB, W1, W2, wpk);
    k_csr<<<NBUCK, 256, 0, stream>>>(store, gcnt, offs, deg, ssrc);

    const int fusedBlocks = N_NODES / BROWS;   // 3125 exactly
    unsigned short* Wp1 = wpk;
    unsigned short* Wp2 = wpk + 3 * DIM * DIM;

    // 3 fused layers: q8 ping-pong
    k_fused<<<fusedBlocks, 128, 0, stream>>>(q8A, sA, offs, deg, ssrc,
                                             q8B, sB,
                                             Wp1, b1, Wp2, b2, 1);
    k_fused<<<fusedBlocks, 128, 0, stream>>>(q8B, sB, offs, deg, ssrc,
                                             q8A, sA,
                                             Wp1 + DIM * DIM, b1 + DIM,
                                             Wp2 + DIM * DIM, b2 + DIM, 1);
    k_fused<<<fusedBlocks, 128, 0, stream>>>(q8A, sA, offs, deg, ssrc,
                                             q8B, sB,
                                             Wp1 + 2 * DIM * DIM, b1 + 2 * DIM,
                                             Wp2 + 2 * DIM * DIM, b2 + 2 * DIM, 0);

    // two-stage pool (stage 1 dequants q8)
    {
        dim3 g1(NGRAPHS, PCHUNK);
        k_pool1<<<g1, 256, 0, stream>>>(q8B, sB, batch, partial);
        k_pool2<<<NGRAPHS, 128, 0, stream>>>(partial, out);
    }
}